// Round 7
// baseline (210.268 us; speedup 1.0000x reference)
//
#include <hip/hip_runtime.h>
#include <hip/hip_bf16.h>
#include <stdint.h>

// bf16 MFMA pipeline, v7. B=2, L=2048, D=1024, H=16, dh=64.
// a2 = softmax(s_prev) is a column permutation of a1 -> o = lam * A1 @ (v - roll(v,-1)).
// v7: diff_attn blocks are 2 waves x 32 q-rows (halves LDS-read traffic per q-row
// vs v6's 4 waves x 16 q); x32 PV via permlane relayout; conflict-free b128 slots.

typedef __attribute__((ext_vector_type(8))) short s16x8;
typedef __attribute__((ext_vector_type(4))) float f32x4;

__device__ __forceinline__ float bf2f(unsigned short u) {
    union { unsigned int i; float f; } x; x.i = ((unsigned int)u) << 16; return x.f;
}
__device__ __forceinline__ unsigned short f2bf(float f) {
    union { float f; unsigned int i; } x; x.f = f;
    unsigned int r = x.i + 0x7FFFu + ((x.i >> 16) & 1u);   // RNE
    return (unsigned short)(r >> 16);
}

// async global->LDS, 16B/lane; LDS dest = wave-uniform base + lane*16
__device__ __forceinline__ void gload16(const void* g, void* l) {
    auto gp = reinterpret_cast<const __attribute__((address_space(1))) unsigned int*>(
        reinterpret_cast<uintptr_t>(g));
    auto lp = reinterpret_cast<__attribute__((address_space(3))) unsigned int*>(
        reinterpret_cast<uintptr_t>(l));
    __builtin_amdgcn_global_load_lds(gp, lp, 16, 0, 0);
}

__global__ __launch_bounds__(256) void cvt_all(
    const float* __restrict__ x, const float* __restrict__ wq,
    const float* __restrict__ wo,
    unsigned short* __restrict__ xb, unsigned short* __restrict__ wqb,
    unsigned short* __restrict__ wob)
{
    int i4 = blockIdx.x * 256 + threadIdx.x;   // float4 index
    const float* src; unsigned short* dst; int off;
    if (i4 < 1048576)            { src = x;  dst = xb;  off = i4; }
    else if (i4 < 1048576 + 786432) { src = wq; dst = wqb; off = i4 - 1048576; }
    else                         { src = wo; dst = wob; off = i4 - 1835008; }
    float4 v = ((const float4*)src)[off];
    ushort4 u;
    u.x = f2bf(v.x); u.y = f2bf(v.y); u.z = f2bf(v.z); u.w = f2bf(v.w);
    ((ushort4*)dst)[off] = u;
}

// vdt[b][h][dh][L] = v[b, j, h, dh] - v[b, (j+1)%L, h, dh], transposed via LDS.
__global__ __launch_bounds__(256) void vd_transpose(
    const unsigned short* __restrict__ qkvb, unsigned short* __restrict__ vdt)
{
    __shared__ unsigned short T[64][72];
    const int tid = threadIdx.x;
    const int j0 = blockIdx.x * 64;
    const int bh = blockIdx.y, b = bh >> 4, h = bh & 15;
    const unsigned short* vb = qkvb + (size_t)b * 2048 * 3072 + 2048 + h * 64;

    int r = tid >> 2, cq = tid & 3;
    int j = j0 + r, jn = (j + 1) & 2047;
    const unsigned short* p0 = vb + (size_t)j  * 3072 + cq * 16;
    const unsigned short* p1 = vb + (size_t)jn * 3072 + cq * 16;
    s16x8 a0 = *(const s16x8*)p0, a1 = *(const s16x8*)(p0 + 8);
    s16x8 b0 = *(const s16x8*)p1, b1 = *(const s16x8*)(p1 + 8);
#pragma unroll
    for (int u = 0; u < 8; ++u)
        T[cq * 16 + u][r] = f2bf(bf2f((unsigned short)a0[u]) - bf2f((unsigned short)b0[u]));
#pragma unroll
    for (int u = 0; u < 8; ++u)
        T[cq * 16 + 8 + u][r] = f2bf(bf2f((unsigned short)a1[u]) - bf2f((unsigned short)b1[u]));
    __syncthreads();

    int row = tid >> 2, sc = tid & 3;
    s16x8 o0 = *(const s16x8*)&T[row][sc * 16];
    s16x8 o1 = *(const s16x8*)&T[row][sc * 16 + 8];
    unsigned short* dst = vdt + ((size_t)bh * 64 + row) * 2048 + j0 + sc * 16;
    *(s16x8*)dst = o0;
    *(s16x8*)(dst + 8) = o1;
}

// C[m,n] = sum_k A[m,k]*Bm[n,k] + bias[n]; cols < nscale additionally *= smul.
template <int OUT_BF16, int BN>
__global__ __launch_bounds__(256) void gemm_nt_mfma(
    const unsigned short* __restrict__ A,
    const unsigned short* __restrict__ Bm,
    const float* __restrict__ bias,
    void* __restrict__ C,
    int M, int N, int K, int nscale, float smul)
{
    constexpr int NT = BN / 32;
    __shared__ unsigned short As[2][128][32];
    __shared__ unsigned short Bs[2][BN][32];

    const int tid = threadIdx.x;
    const int wave = tid >> 6, lane = tid & 63;
    const int quad = lane >> 4, ln = lane & 15;
    const int wm = (wave >> 1) * 64, wn = (wave & 1) * (NT * 16);
    const int m0 = blockIdx.y * 128, n0 = blockIdx.x * BN;
    const int rA = wave * 16 + (lane >> 2);
    const int gsl = lane & 3;

    f32x4 acc[4][NT];
#pragma unroll
    for (int mt = 0; mt < 4; ++mt)
#pragma unroll
        for (int nt = 0; nt < NT; ++nt) acc[mt][nt] = f32x4{0.f, 0.f, 0.f, 0.f};

    auto stage = [&](int p, int k0) {
#pragma unroll
        for (int q = 0; q < 2; ++q) {
            int row = q * 64 + rA;
            int kg = gsl ^ ((row >> 1) & 3);
            gload16(A + (size_t)(m0 + row) * K + k0 + kg * 8,
                    &As[p][q * 64 + wave * 16][0]);
            if (q * 64 < BN)
                gload16(Bm + (size_t)(n0 + row) * K + k0 + kg * 8,
                        &Bs[p][q * 64 + wave * 16][0]);
        }
    };

    stage(0, 0);
    __syncthreads();
    int p = 0;
    for (int k0 = 0; k0 < K; k0 += 32) {
        if (k0 + 32 < K) stage(p ^ 1, k0 + 32);
        s16x8 af[4], bfr[NT];
#pragma unroll
        for (int mt = 0; mt < 4; ++mt) {
            int rr = wm + mt * 16 + ln;
            af[mt] = *(const s16x8*)&As[p][rr][((quad ^ ((rr >> 1) & 3)) & 3) * 8];
        }
#pragma unroll
        for (int nt = 0; nt < NT; ++nt) {
            int rr = wn + nt * 16 + ln;
            bfr[nt] = *(const s16x8*)&Bs[p][rr][((quad ^ ((rr >> 1) & 3)) & 3) * 8];
        }
#pragma unroll
        for (int mt = 0; mt < 4; ++mt)
#pragma unroll
            for (int nt = 0; nt < NT; ++nt)
                acc[mt][nt] = __builtin_amdgcn_mfma_f32_16x16x32_bf16(
                    af[mt], bfr[nt], acc[mt][nt], 0, 0, 0);
        __syncthreads();
        p ^= 1;
    }

    float bb[NT];
#pragma unroll
    for (int nt = 0; nt < NT; ++nt) bb[nt] = bias[n0 + wn + nt * 16 + ln];
#pragma unroll
    for (int mt = 0; mt < 4; ++mt)
#pragma unroll
        for (int nt = 0; nt < NT; ++nt) {
            int col = n0 + wn + nt * 16 + ln;
            float sc = (col < nscale) ? smul : 1.f;
#pragma unroll
            for (int rg = 0; rg < 4; ++rg) {
                int row = m0 + wm + mt * 16 + quad * 4 + rg;
                float v = (acc[mt][nt][rg] + bb[nt]) * sc;
                if (OUT_BF16)
                    ((unsigned short*)C)[(size_t)row * N + col] = f2bf(v);
                else
                    ((float*)C)[(size_t)row * N + col] = v;
            }
        }
}

// Differential attention, v7. 2 waves/block; wave owns 32 q-rows (2 x 16-row groups);
// block = 64 q-rows; grid (32,32) -> 4-5 blocks/CU.
__global__ __launch_bounds__(128) void diff_attn_v7(
    const unsigned short* __restrict__ qkv,   // [B*L][3072] bf16 (Q pre-scaled by log2e/32)
    const unsigned short* __restrict__ vdt,   // [B*H][64][2048] bf16
    const float* __restrict__ lam_p,
    unsigned short* __restrict__ o_ws)        // [B*L][1024] bf16
{
    constexpr int L = 2048, TD = 3072;

    __shared__ unsigned short Ks[2][64][64];  // [seq][dh], chunk-swizzled
    __shared__ unsigned short Vs[2][64][64];  // [dh][seq], chunk-swizzled

    const int tid = threadIdx.x;
    const int wave = tid >> 6, lane = tid & 63;
    const int quad = lane >> 4, ln = lane & 15;
    const int bh = blockIdx.y, b = bh >> 4, h = bh & 15;
    const int q0 = blockIdx.x * 64;
    const size_t seqbase = (size_t)b * L;
    const unsigned short* base = qkv + seqbase * TD + h * 64;
    const unsigned short* kb = base + 1024;
    const unsigned short* vbase = vdt + (size_t)bh * 64 * 2048;

    const int lsl = lane >> 3;
    const int cgl = (lane & 7) ^ lsl;

    // Q fragments for both q-groups (B-operand of S^T MFMA: n=ln -> q, k=quad*8+u -> d)
    s16x8 qf[2][2];
#pragma unroll
    for (int s = 0; s < 2; ++s) {
        const unsigned short* qrow =
            base + (size_t)(q0 + wave * 32 + s * 16 + ln) * TD;
        qf[s][0] = *(const s16x8*)(qrow + quad * 8);
        qf[s][1] = *(const s16x8*)(qrow + 32 + quad * 8);
    }

    // staging: each wave covers 32 rows of K and V (4 gload16 each)
    auto stage = [&](int p, int j0) {
        const unsigned short* k0p = kb + (size_t)(j0 + wave * 32 + lsl) * TD + cgl * 8;
#pragma unroll
        for (int rr = 0; rr < 4; ++rr)
            gload16(k0p + (size_t)(8 * rr) * TD, &Ks[p][wave * 32 + 8 * rr][0]);
        const unsigned short* v0p =
            vbase + (size_t)(wave * 32 + lsl) * 2048 + j0 + cgl * 8;
#pragma unroll
        for (int rr = 0; rr < 4; ++rr)
            gload16(v0p + 8 * rr * 2048, &Vs[p][wave * 32 + 8 * rr][0]);
    };

    f32x4 Ot[2][4];   // O^T accumulators: q=ln, d = mt*16 + quad*4 + rg
    f32x4 lacc[2];    // row-sum accumulators via ones-MFMA (all rg equal)
#pragma unroll
    for (int s = 0; s < 2; ++s) {
        lacc[s] = f32x4{0.f, 0.f, 0.f, 0.f};
#pragma unroll
        for (int mt = 0; mt < 4; ++mt) Ot[s][mt] = f32x4{0.f, 0.f, 0.f, 0.f};
    }

    const s16x8 ones8 = {(short)0x3F80, (short)0x3F80, (short)0x3F80, (short)0x3F80,
                         (short)0x3F80, (short)0x3F80, (short)0x3F80, (short)0x3F80};
    const int kx0 = (quad ^ (ln & 7)) << 3;        // chunk quad
    const int kx1 = ((quad + 4) ^ (ln & 7)) << 3;  // chunk quad+4

    stage(0, 0);
    __syncthreads();
    int p = 0;
    for (int kt = 0; kt < 32; ++kt) {
        if (kt + 1 < 32) stage(p ^ 1, (kt + 1) * 64);

        // ---- S^T = K Q^T: A = K-frag (m=j), B = qf (n=q); K-frags shared across s.
        //      C-layout: col=ln -> q, row=quad*4+rg -> j = t*16 + quad*4 + rg
        f32x4 ST[2][4];
#pragma unroll
        for (int t = 0; t < 4; ++t) {
            s16x8 k0 = *(const s16x8*)&Ks[p][t * 16 + ln][kx0];
            s16x8 k1 = *(const s16x8*)&Ks[p][t * 16 + ln][kx1];
#pragma unroll
            for (int s = 0; s < 2; ++s) {
                f32x4 z = f32x4{0.f, 0.f, 0.f, 0.f};
                z = __builtin_amdgcn_mfma_f32_16x16x32_bf16(k0, qf[s][0], z, 0, 0, 0);
                z = __builtin_amdgcn_mfma_f32_16x16x32_bf16(k1, qf[s][1], z, 0, 0, 0);
                ST[s][t] = z;
            }
        }

        // ---- per q-group: exp2, pack, permlane relayout, lsum ----
        s16x8 pfr[2][2];
#pragma unroll
        for (int s = 0; s < 2; ++s) {
            uint2 pk[4];
#pragma unroll
            for (int t = 0; t < 4; ++t) {
                unsigned int e0 = __builtin_bit_cast(unsigned int, __builtin_amdgcn_exp2f(ST[s][t][0]));
                unsigned int e1 = __builtin_bit_cast(unsigned int, __builtin_amdgcn_exp2f(ST[s][t][1]));
                unsigned int e2 = __builtin_bit_cast(unsigned int, __builtin_amdgcn_exp2f(ST[s][t][2]));
                unsigned int e3 = __builtin_bit_cast(unsigned int, __builtin_amdgcn_exp2f(ST[s][t][3]));
                pk[t].x = (e0 >> 16) | (e1 & 0xFFFF0000u);
                pk[t].y = (e2 >> 16) | (e3 & 0xFFFF0000u);
            }
            // C-frag -> x32 B-frag relayout via permlane swaps (gfx950 VALU)
#pragma unroll
            for (int bb = 0; bb < 2; ++bb) {
                unsigned int a0 = pk[2 * bb].x, b0 = pk[2 * bb + 1].x;
                unsigned int a1 = pk[2 * bb].y, b1 = pk[2 * bb + 1].y;
                asm volatile("v_permlane32_swap_b32 %0, %1" : "+v"(a0), "+v"(b0));
                asm volatile("v_permlane16_swap_b32 %0, %1" : "+v"(a0), "+v"(b0));
                asm volatile("v_permlane32_swap_b32 %0, %1" : "+v"(a1), "+v"(b1));
                asm volatile("v_permlane16_swap_b32 %0, %1" : "+v"(a1), "+v"(b1));
                uint4 fr = make_uint4(a0, a1, b0, b1);
                pfr[s][bb] = __builtin_bit_cast(s16x8, fr);
            }
            // row sums l[q] += sum_j P^T[j][q] via ones-MFMA
            lacc[s] = __builtin_amdgcn_mfma_f32_16x16x32_bf16(ones8, pfr[s][0], lacc[s], 0, 0, 0);
            lacc[s] = __builtin_amdgcn_mfma_f32_16x16x32_bf16(ones8, pfr[s][1], lacc[s], 0, 0, 0);
        }

        // ---- O^T += Vd^T P^T (A = Vd^T b128 frag, shared across s) ----
#pragma unroll
        for (int bb = 0; bb < 2; ++bb) {
            const int kx = bb ? kx1 : kx0;   // chunk 4*bb + quad
#pragma unroll
            for (int mt = 0; mt < 4; ++mt) {
                s16x8 vf = *(const s16x8*)&Vs[p][mt * 16 + ln][kx];
#pragma unroll
                for (int s = 0; s < 2; ++s)
                    Ot[s][mt] = __builtin_amdgcn_mfma_f32_16x16x32_bf16(
                        vf, pfr[s][bb], Ot[s][mt], 0, 0, 0);
            }
        }
        __syncthreads();
        p ^= 1;
    }

    const float lam = lam_p[0];
#pragma unroll
    for (int s = 0; s < 2; ++s) {
        float inv = lam / lacc[s][0];
        int row = q0 + wave * 32 + s * 16 + ln;
        unsigned short* orow = o_ws + (seqbase + row) * 1024 + h * 64 + quad * 4;
#pragma unroll
        for (int mt = 0; mt < 4; ++mt) {
            ushort4 u;
            u.x = f2bf(Ot[s][mt][0] * inv);
            u.y = f2bf(Ot[s][mt][1] * inv);
            u.z = f2bf(Ot[s][mt][2] * inv);
            u.w = f2bf(Ot[s][mt][3] * inv);
            *(ushort4*)(orow + mt * 16) = u;
        }
    }
}

extern "C" void kernel_launch(void* const* d_in, const int* in_sizes, int n_in,
                              void* d_out, int out_size, void* d_ws, size_t ws_size,
                              hipStream_t stream) {
    const float* x     = (const float*)d_in[0];
    const float* w_qkv = (const float*)d_in[1];
    const float* b_qkv = (const float*)d_in[2];
    const float* w_out = (const float*)d_in[3];
    const float* b_out = (const float*)d_in[4];
    const float* lam   = (const float*)d_in[5];
    float* out = (float*)d_out;

    unsigned short* xb   = (unsigned short*)d_ws;
    unsigned short* wqb  = xb   + (size_t)4096 * 1024;
    unsigned short* wob  = wqb  + (size_t)3072 * 1024;
    unsigned short* qkvb = wob  + (size_t)1024 * 1024;
    unsigned short* ob   = qkvb + (size_t)4096 * 3072;
    unsigned short* vdt  = ob   + (size_t)4096 * 1024;

    cvt_all<<<8192, 256, 0, stream>>>(x, w_qkv, w_out, xb, wqb, wob);

    // qkv = x @ w_qkv^T + b_qkv; Q cols (n<1024) pre-scaled by log2(e)/32
    gemm_nt_mfma<1, 128><<<dim3(24, 32), 256, 0, stream>>>(
        xb, wqb, b_qkv, qkvb, 4096, 3072, 1024, 1024, 0.045084222f);

    vd_transpose<<<dim3(32, 32), 256, 0, stream>>>(qkvb, vdt);

    diff_attn_v7<<<dim3(32, 32), 128, 0, stream>>>(qkvb, vdt, lam, ob);

    gemm_nt_mfma<0, 64><<<dim3(16, 32), 256, 0, stream>>>(
        ob, wob, b_out, out, 4096, 1024, 1024, 0, 1.f);
}

// Round 8
// 208.598 us; speedup vs baseline: 1.0080x; 1.0080x over previous
//
#include <hip/hip_runtime.h>
#include <hip/hip_bf16.h>
#include <stdint.h>

// bf16 MFMA pipeline, v8. B=2, L=2048, D=1024, H=16, dh=64.
// a2 = softmax(s_prev) is a column permutation of a1 -> o = lam * A1 @ (v - roll(v,-1)).
// v8: diff_attn = v6 exact revert (4 waves x 16q, best measured); GEMMs use 128x64
// tiles (6 blocks/CU) to cover the vmcnt(0)+barrier drain at K=1024.

typedef __attribute__((ext_vector_type(8))) short s16x8;
typedef __attribute__((ext_vector_type(4))) float f32x4;

__device__ __forceinline__ float bf2f(unsigned short u) {
    union { unsigned int i; float f; } x; x.i = ((unsigned int)u) << 16; return x.f;
}
__device__ __forceinline__ unsigned short f2bf(float f) {
    union { float f; unsigned int i; } x; x.f = f;
    unsigned int r = x.i + 0x7FFFu + ((x.i >> 16) & 1u);   // RNE
    return (unsigned short)(r >> 16);
}

// async global->LDS, 16B/lane; LDS dest = wave-uniform base + lane*16
__device__ __forceinline__ void gload16(const void* g, void* l) {
    auto gp = reinterpret_cast<const __attribute__((address_space(1))) unsigned int*>(
        reinterpret_cast<uintptr_t>(g));
    auto lp = reinterpret_cast<__attribute__((address_space(3))) unsigned int*>(
        reinterpret_cast<uintptr_t>(l));
    __builtin_amdgcn_global_load_lds(gp, lp, 16, 0, 0);
}

__global__ __launch_bounds__(256) void cvt_all(
    const float* __restrict__ x, const float* __restrict__ wq,
    const float* __restrict__ wo,
    unsigned short* __restrict__ xb, unsigned short* __restrict__ wqb,
    unsigned short* __restrict__ wob)
{
    int i4 = blockIdx.x * 256 + threadIdx.x;   // float4 index
    const float* src; unsigned short* dst; int off;
    if (i4 < 1048576)            { src = x;  dst = xb;  off = i4; }
    else if (i4 < 1048576 + 786432) { src = wq; dst = wqb; off = i4 - 1048576; }
    else                         { src = wo; dst = wob; off = i4 - 1835008; }
    float4 v = ((const float4*)src)[off];
    ushort4 u;
    u.x = f2bf(v.x); u.y = f2bf(v.y); u.z = f2bf(v.z); u.w = f2bf(v.w);
    ((ushort4*)dst)[off] = u;
}

// vdt[b][h][dh][L] = v[b, j, h, dh] - v[b, (j+1)%L, h, dh], transposed via LDS.
__global__ __launch_bounds__(256) void vd_transpose(
    const unsigned short* __restrict__ qkvb, unsigned short* __restrict__ vdt)
{
    __shared__ unsigned short T[64][72];
    const int tid = threadIdx.x;
    const int j0 = blockIdx.x * 64;
    const int bh = blockIdx.y, b = bh >> 4, h = bh & 15;
    const unsigned short* vb = qkvb + (size_t)b * 2048 * 3072 + 2048 + h * 64;

    int r = tid >> 2, cq = tid & 3;
    int j = j0 + r, jn = (j + 1) & 2047;
    const unsigned short* p0 = vb + (size_t)j  * 3072 + cq * 16;
    const unsigned short* p1 = vb + (size_t)jn * 3072 + cq * 16;
    s16x8 a0 = *(const s16x8*)p0, a1 = *(const s16x8*)(p0 + 8);
    s16x8 b0 = *(const s16x8*)p1, b1 = *(const s16x8*)(p1 + 8);
#pragma unroll
    for (int u = 0; u < 8; ++u)
        T[cq * 16 + u][r] = f2bf(bf2f((unsigned short)a0[u]) - bf2f((unsigned short)b0[u]));
#pragma unroll
    for (int u = 0; u < 8; ++u)
        T[cq * 16 + 8 + u][r] = f2bf(bf2f((unsigned short)a1[u]) - bf2f((unsigned short)b1[u]));
    __syncthreads();

    int row = tid >> 2, sc = tid & 3;
    s16x8 o0 = *(const s16x8*)&T[row][sc * 16];
    s16x8 o1 = *(const s16x8*)&T[row][sc * 16 + 8];
    unsigned short* dst = vdt + ((size_t)bh * 64 + row) * 2048 + j0 + sc * 16;
    *(s16x8*)dst = o0;
    *(s16x8*)(dst + 8) = o1;
}

// C[m,n] = sum_k A[m,k]*Bm[n,k] + bias[n]; cols < nscale additionally *= smul.
// Block tile 128 x BN; 4 waves 2x2; BN=64 -> 24KB LDS -> 6 blocks/CU.
template <int OUT_BF16, int BN>
__global__ __launch_bounds__(256) void gemm_nt_mfma(
    const unsigned short* __restrict__ A,
    const unsigned short* __restrict__ Bm,
    const float* __restrict__ bias,
    void* __restrict__ C,
    int M, int N, int K, int nscale, float smul)
{
    constexpr int NT = BN / 32;
    __shared__ unsigned short As[2][128][32];
    __shared__ unsigned short Bs[2][BN][32];

    const int tid = threadIdx.x;
    const int wave = tid >> 6, lane = tid & 63;
    const int quad = lane >> 4, ln = lane & 15;
    const int wm = (wave >> 1) * 64, wn = (wave & 1) * (NT * 16);
    const int m0 = blockIdx.y * 128, n0 = blockIdx.x * BN;
    const int rA = wave * 16 + (lane >> 2);
    const int gsl = lane & 3;

    f32x4 acc[4][NT];
#pragma unroll
    for (int mt = 0; mt < 4; ++mt)
#pragma unroll
        for (int nt = 0; nt < NT; ++nt) acc[mt][nt] = f32x4{0.f, 0.f, 0.f, 0.f};

    auto stage = [&](int p, int k0) {
#pragma unroll
        for (int q = 0; q < 2; ++q) {
            int row = q * 64 + rA;
            int kg = gsl ^ ((row >> 1) & 3);
            gload16(A + (size_t)(m0 + row) * K + k0 + kg * 8,
                    &As[p][q * 64 + wave * 16][0]);
            if (q * 64 < BN)
                gload16(Bm + (size_t)(n0 + row) * K + k0 + kg * 8,
                        &Bs[p][q * 64 + wave * 16][0]);
        }
    };

    stage(0, 0);
    __syncthreads();
    int p = 0;
    for (int k0 = 0; k0 < K; k0 += 32) {
        if (k0 + 32 < K) stage(p ^ 1, k0 + 32);
        s16x8 af[4], bfr[NT];
#pragma unroll
        for (int mt = 0; mt < 4; ++mt) {
            int rr = wm + mt * 16 + ln;
            af[mt] = *(const s16x8*)&As[p][rr][((quad ^ ((rr >> 1) & 3)) & 3) * 8];
        }
#pragma unroll
        for (int nt = 0; nt < NT; ++nt) {
            int rr = wn + nt * 16 + ln;
            bfr[nt] = *(const s16x8*)&Bs[p][rr][((quad ^ ((rr >> 1) & 3)) & 3) * 8];
        }
#pragma unroll
        for (int mt = 0; mt < 4; ++mt)
#pragma unroll
            for (int nt = 0; nt < NT; ++nt)
                acc[mt][nt] = __builtin_amdgcn_mfma_f32_16x16x32_bf16(
                    af[mt], bfr[nt], acc[mt][nt], 0, 0, 0);
        __syncthreads();
        p ^= 1;
    }

    float bb[NT];
#pragma unroll
    for (int nt = 0; nt < NT; ++nt) bb[nt] = bias[n0 + wn + nt * 16 + ln];
#pragma unroll
    for (int mt = 0; mt < 4; ++mt)
#pragma unroll
        for (int nt = 0; nt < NT; ++nt) {
            int col = n0 + wn + nt * 16 + ln;
            float sc = (col < nscale) ? smul : 1.f;
#pragma unroll
            for (int rg = 0; rg < 4; ++rg) {
                int row = m0 + wm + mt * 16 + quad * 4 + rg;
                float v = (acc[mt][nt][rg] + bb[nt]) * sc;
                if (OUT_BF16)
                    ((unsigned short*)C)[(size_t)row * N + col] = f2bf(v);
                else
                    ((float*)C)[(size_t)row * N + col] = v;
            }
        }
}

// Differential attention, v6 (best measured). Wave owns 16 q-rows; block = 64 q-rows;
// grid (32,32). S^T C-frag -> x32 B-frag relayout via permlane{32,16}_swap.
__global__ __launch_bounds__(256) void diff_attn_v6(
    const unsigned short* __restrict__ qkv,   // [B*L][3072] bf16 (Q pre-scaled by log2e/32)
    const unsigned short* __restrict__ vdt,   // [B*H][64][2048] bf16
    const float* __restrict__ lam_p,
    unsigned short* __restrict__ o_ws)        // [B*L][1024] bf16
{
    constexpr int L = 2048, TD = 3072;

    __shared__ unsigned short Ks[2][64][64];  // [seq][dh], chunk-swizzled
    __shared__ unsigned short Vs[2][64][64];  // [dh][seq], chunk-swizzled

    const int tid = threadIdx.x;
    const int wave = tid >> 6, lane = tid & 63;
    const int quad = lane >> 4, ln = lane & 15;
    const int bh = blockIdx.y, b = bh >> 4, h = bh & 15;
    const int q0 = blockIdx.x * 64;
    const size_t seqbase = (size_t)b * L;
    const unsigned short* base = qkv + seqbase * TD + h * 64;
    const unsigned short* kb = base + 1024;
    const unsigned short* vbase = vdt + (size_t)bh * 64 * 2048;

    const int lsl = lane >> 3;
    const int cgl = (lane & 7) ^ lsl;

    // Q fragments (B-operand of S^T MFMA: n=ln -> q, k=quad*8+u -> d)
    s16x8 qf0, qf1;
    {
        const unsigned short* qrow = base + (size_t)(q0 + wave * 16 + ln) * TD;
        qf0 = *(const s16x8*)(qrow + quad * 8);
        qf1 = *(const s16x8*)(qrow + 32 + quad * 8);
    }

    auto stage = [&](int p, int j0) {
        const unsigned short* k0p = kb + (size_t)(j0 + wave * 16 + lsl) * TD + cgl * 8;
        gload16(k0p,                  &Ks[p][wave * 16][0]);
        gload16(k0p + (size_t)8 * TD, &Ks[p][wave * 16 + 8][0]);
        const unsigned short* v0p = vbase + (size_t)(wave * 16 + lsl) * 2048 + j0 + cgl * 8;
        gload16(v0p,            &Vs[p][wave * 16][0]);
        gload16(v0p + 8 * 2048, &Vs[p][wave * 16 + 8][0]);
    };

    f32x4 Ot[4];     // O^T accumulators: q=ln, d = mt*16 + quad*4 + rg
    f32x4 lacc;      // row-sum accumulator via ones-MFMA (all rg equal)
    lacc = f32x4{0.f, 0.f, 0.f, 0.f};
#pragma unroll
    for (int mt = 0; mt < 4; ++mt) Ot[mt] = f32x4{0.f, 0.f, 0.f, 0.f};

    const s16x8 ones8 = {(short)0x3F80, (short)0x3F80, (short)0x3F80, (short)0x3F80,
                         (short)0x3F80, (short)0x3F80, (short)0x3F80, (short)0x3F80};
    const int kx0 = (quad ^ (ln & 7)) << 3;        // chunk quad
    const int kx1 = ((quad + 4) ^ (ln & 7)) << 3;  // chunk quad+4

    stage(0, 0);
    __syncthreads();
    int p = 0;
    for (int kt = 0; kt < 32; ++kt) {
        if (kt + 1 < 32) stage(p ^ 1, (kt + 1) * 64);

        // ---- S^T = K Q^T: A = K-frag (m=j), B = qf (n=q).
        //      C-layout: col=ln -> q, row=quad*4+rg -> j = t*16 + quad*4 + rg
        f32x4 ST[4];
#pragma unroll
        for (int t = 0; t < 4; ++t) {
            s16x8 k0 = *(const s16x8*)&Ks[p][t * 16 + ln][kx0];
            s16x8 k1 = *(const s16x8*)&Ks[p][t * 16 + ln][kx1];
            f32x4 z = f32x4{0.f, 0.f, 0.f, 0.f};
            z = __builtin_amdgcn_mfma_f32_16x16x32_bf16(k0, qf0, z, 0, 0, 0);
            z = __builtin_amdgcn_mfma_f32_16x16x32_bf16(k1, qf1, z, 0, 0, 0);
            ST[t] = z;
        }

        // ---- P^T = exp2(S^T), truncate-pack to bf16 pairs (lsum eats same values) ----
        uint2 pk[4];
#pragma unroll
        for (int t = 0; t < 4; ++t) {
            unsigned int e0 = __builtin_bit_cast(unsigned int, __builtin_amdgcn_exp2f(ST[t][0]));
            unsigned int e1 = __builtin_bit_cast(unsigned int, __builtin_amdgcn_exp2f(ST[t][1]));
            unsigned int e2 = __builtin_bit_cast(unsigned int, __builtin_amdgcn_exp2f(ST[t][2]));
            unsigned int e3 = __builtin_bit_cast(unsigned int, __builtin_amdgcn_exp2f(ST[t][3]));
            pk[t].x = (e0 >> 16) | (e1 & 0xFFFF0000u);
            pk[t].y = (e2 >> 16) | (e3 & 0xFFFF0000u);
        }

        // ---- C-frag -> x32 B-frag relayout via permlane swaps (gfx950 VALU) ----
        s16x8 pfr[2];
#pragma unroll
        for (int bb = 0; bb < 2; ++bb) {
            unsigned int a0 = pk[2 * bb].x, b0 = pk[2 * bb + 1].x;
            unsigned int a1 = pk[2 * bb].y, b1 = pk[2 * bb + 1].y;
            asm volatile("v_permlane32_swap_b32 %0, %1" : "+v"(a0), "+v"(b0));
            asm volatile("v_permlane16_swap_b32 %0, %1" : "+v"(a0), "+v"(b0));
            asm volatile("v_permlane32_swap_b32 %0, %1" : "+v"(a1), "+v"(b1));
            asm volatile("v_permlane16_swap_b32 %0, %1" : "+v"(a1), "+v"(b1));
            uint4 fr = make_uint4(a0, a1, b0, b1);
            pfr[bb] = __builtin_bit_cast(s16x8, fr);
        }

        // ---- row sums l[q] += sum_j P^T[j][q] via ones-MFMA ----
        lacc = __builtin_amdgcn_mfma_f32_16x16x32_bf16(ones8, pfr[0], lacc, 0, 0, 0);
        lacc = __builtin_amdgcn_mfma_f32_16x16x32_bf16(ones8, pfr[1], lacc, 0, 0, 0);

        // ---- O^T += Vd^T P^T (A = Vd^T b128 frag, conflict-free slots) ----
#pragma unroll
        for (int bb = 0; bb < 2; ++bb) {
            const int kx = bb ? kx1 : kx0;   // chunk 4*bb + quad
#pragma unroll
            for (int mt = 0; mt < 4; ++mt) {
                s16x8 vf = *(const s16x8*)&Vs[p][mt * 16 + ln][kx];
                Ot[mt] = __builtin_amdgcn_mfma_f32_16x16x32_bf16(vf, pfr[bb], Ot[mt], 0, 0, 0);
            }
        }
        __syncthreads();
        p ^= 1;
    }

    const float lam = lam_p[0];
    {
        float inv = lam / lacc[0];
        int row = q0 + wave * 16 + ln;
        unsigned short* orow = o_ws + (seqbase + row) * 1024 + h * 64 + quad * 4;
#pragma unroll
        for (int mt = 0; mt < 4; ++mt) {
            ushort4 u;
            u.x = f2bf(Ot[mt][0] * inv);
            u.y = f2bf(Ot[mt][1] * inv);
            u.z = f2bf(Ot[mt][2] * inv);
            u.w = f2bf(Ot[mt][3] * inv);
            *(ushort4*)(orow + mt * 16) = u;
        }
    }
}

extern "C" void kernel_launch(void* const* d_in, const int* in_sizes, int n_in,
                              void* d_out, int out_size, void* d_ws, size_t ws_size,
                              hipStream_t stream) {
    const float* x     = (const float*)d_in[0];
    const float* w_qkv = (const float*)d_in[1];
    const float* b_qkv = (const float*)d_in[2];
    const float* w_out = (const float*)d_in[3];
    const float* b_out = (const float*)d_in[4];
    const float* lam   = (const float*)d_in[5];
    float* out = (float*)d_out;

    unsigned short* xb   = (unsigned short*)d_ws;
    unsigned short* wqb  = xb   + (size_t)4096 * 1024;
    unsigned short* wob  = wqb  + (size_t)3072 * 1024;
    unsigned short* qkvb = wob  + (size_t)1024 * 1024;
    unsigned short* ob   = qkvb + (size_t)4096 * 3072;
    unsigned short* vdt  = ob   + (size_t)4096 * 1024;

    cvt_all<<<8192, 256, 0, stream>>>(x, w_qkv, w_out, xb, wqb, wob);

    // qkv = x @ w_qkv^T + b_qkv; Q cols (n<1024) pre-scaled by log2(e)/32
    // 128x64 tiles -> 48x32 = 1536 blocks = 6/CU (barrier-drain cover at K=1024)
    gemm_nt_mfma<1, 64><<<dim3(48, 32), 256, 0, stream>>>(
        xb, wqb, b_qkv, qkvb, 4096, 3072, 1024, 1024, 0.045084222f);

    vd_transpose<<<dim3(32, 32), 256, 0, stream>>>(qkvb, vdt);

    diff_attn_v6<<<dim3(32, 32), 256, 0, stream>>>(qkvb, vdt, lam, ob);

    gemm_nt_mfma<0, 64><<<dim3(16, 32), 256, 0, stream>>>(
        ob, wob, b_out, out, 4096, 1024, 1024, 0, 1.f);
}

// Round 9
// 199.378 us; speedup vs baseline: 1.0546x; 1.0462x over previous
//
#include <hip/hip_runtime.h>
#include <hip/hip_bf16.h>
#include <stdint.h>

// bf16 MFMA pipeline, v9. B=2, L=2048, D=1024, H=16, dh=64.
// a2 = softmax(s_prev) is a column permutation of a1 -> o = lam * A1 @ (v - roll(v,-1)).
// v9 = R6 best config (gemm1 128x128, gemm2 128x64, diff_attn v6) + diff_attn VALU
// trim: v_perm_b32 packing, incremental staging pointers.

typedef __attribute__((ext_vector_type(8))) short s16x8;
typedef __attribute__((ext_vector_type(4))) float f32x4;

__device__ __forceinline__ float bf2f(unsigned short u) {
    union { unsigned int i; float f; } x; x.i = ((unsigned int)u) << 16; return x.f;
}
__device__ __forceinline__ unsigned short f2bf(float f) {
    union { float f; unsigned int i; } x; x.f = f;
    unsigned int r = x.i + 0x7FFFu + ((x.i >> 16) & 1u);   // RNE
    return (unsigned short)(r >> 16);
}

// async global->LDS, 16B/lane; LDS dest = wave-uniform base + lane*16
__device__ __forceinline__ void gload16(const void* g, void* l) {
    auto gp = reinterpret_cast<const __attribute__((address_space(1))) unsigned int*>(
        reinterpret_cast<uintptr_t>(g));
    auto lp = reinterpret_cast<__attribute__((address_space(3))) unsigned int*>(
        reinterpret_cast<uintptr_t>(l));
    __builtin_amdgcn_global_load_lds(gp, lp, 16, 0, 0);
}

__global__ __launch_bounds__(256) void cvt_all(
    const float* __restrict__ x, const float* __restrict__ wq,
    const float* __restrict__ wo,
    unsigned short* __restrict__ xb, unsigned short* __restrict__ wqb,
    unsigned short* __restrict__ wob)
{
    int i4 = blockIdx.x * 256 + threadIdx.x;   // float4 index
    const float* src; unsigned short* dst; int off;
    if (i4 < 1048576)            { src = x;  dst = xb;  off = i4; }
    else if (i4 < 1048576 + 786432) { src = wq; dst = wqb; off = i4 - 1048576; }
    else                         { src = wo; dst = wob; off = i4 - 1835008; }
    float4 v = ((const float4*)src)[off];
    ushort4 u;
    u.x = f2bf(v.x); u.y = f2bf(v.y); u.z = f2bf(v.z); u.w = f2bf(v.w);
    ((ushort4*)dst)[off] = u;
}

// vdt[b][h][dh][L] = v[b, j, h, dh] - v[b, (j+1)%L, h, dh], transposed via LDS.
__global__ __launch_bounds__(256) void vd_transpose(
    const unsigned short* __restrict__ qkvb, unsigned short* __restrict__ vdt)
{
    __shared__ unsigned short T[64][72];
    const int tid = threadIdx.x;
    const int j0 = blockIdx.x * 64;
    const int bh = blockIdx.y, b = bh >> 4, h = bh & 15;
    const unsigned short* vb = qkvb + (size_t)b * 2048 * 3072 + 2048 + h * 64;

    int r = tid >> 2, cq = tid & 3;
    int j = j0 + r, jn = (j + 1) & 2047;
    const unsigned short* p0 = vb + (size_t)j  * 3072 + cq * 16;
    const unsigned short* p1 = vb + (size_t)jn * 3072 + cq * 16;
    s16x8 a0 = *(const s16x8*)p0, a1 = *(const s16x8*)(p0 + 8);
    s16x8 b0 = *(const s16x8*)p1, b1 = *(const s16x8*)(p1 + 8);
#pragma unroll
    for (int u = 0; u < 8; ++u)
        T[cq * 16 + u][r] = f2bf(bf2f((unsigned short)a0[u]) - bf2f((unsigned short)b0[u]));
#pragma unroll
    for (int u = 0; u < 8; ++u)
        T[cq * 16 + 8 + u][r] = f2bf(bf2f((unsigned short)a1[u]) - bf2f((unsigned short)b1[u]));
    __syncthreads();

    int row = tid >> 2, sc = tid & 3;
    s16x8 o0 = *(const s16x8*)&T[row][sc * 16];
    s16x8 o1 = *(const s16x8*)&T[row][sc * 16 + 8];
    unsigned short* dst = vdt + ((size_t)bh * 64 + row) * 2048 + j0 + sc * 16;
    *(s16x8*)dst = o0;
    *(s16x8*)(dst + 8) = o1;
}

// C[m,n] = sum_k A[m,k]*Bm[n,k] + bias[n]; cols < nscale additionally *= smul.
template <int OUT_BF16, int BN>
__global__ __launch_bounds__(256) void gemm_nt_mfma(
    const unsigned short* __restrict__ A,
    const unsigned short* __restrict__ Bm,
    const float* __restrict__ bias,
    void* __restrict__ C,
    int M, int N, int K, int nscale, float smul)
{
    constexpr int NT = BN / 32;
    __shared__ unsigned short As[2][128][32];
    __shared__ unsigned short Bs[2][BN][32];

    const int tid = threadIdx.x;
    const int wave = tid >> 6, lane = tid & 63;
    const int quad = lane >> 4, ln = lane & 15;
    const int wm = (wave >> 1) * 64, wn = (wave & 1) * (NT * 16);
    const int m0 = blockIdx.y * 128, n0 = blockIdx.x * BN;
    const int rA = wave * 16 + (lane >> 2);
    const int gsl = lane & 3;

    f32x4 acc[4][NT];
#pragma unroll
    for (int mt = 0; mt < 4; ++mt)
#pragma unroll
        for (int nt = 0; nt < NT; ++nt) acc[mt][nt] = f32x4{0.f, 0.f, 0.f, 0.f};

    auto stage = [&](int p, int k0) {
#pragma unroll
        for (int q = 0; q < 2; ++q) {
            int row = q * 64 + rA;
            int kg = gsl ^ ((row >> 1) & 3);
            gload16(A + (size_t)(m0 + row) * K + k0 + kg * 8,
                    &As[p][q * 64 + wave * 16][0]);
            if (q * 64 < BN)
                gload16(Bm + (size_t)(n0 + row) * K + k0 + kg * 8,
                        &Bs[p][q * 64 + wave * 16][0]);
        }
    };

    stage(0, 0);
    __syncthreads();
    int p = 0;
    for (int k0 = 0; k0 < K; k0 += 32) {
        if (k0 + 32 < K) stage(p ^ 1, k0 + 32);
        s16x8 af[4], bfr[NT];
#pragma unroll
        for (int mt = 0; mt < 4; ++mt) {
            int rr = wm + mt * 16 + ln;
            af[mt] = *(const s16x8*)&As[p][rr][((quad ^ ((rr >> 1) & 3)) & 3) * 8];
        }
#pragma unroll
        for (int nt = 0; nt < NT; ++nt) {
            int rr = wn + nt * 16 + ln;
            bfr[nt] = *(const s16x8*)&Bs[p][rr][((quad ^ ((rr >> 1) & 3)) & 3) * 8];
        }
#pragma unroll
        for (int mt = 0; mt < 4; ++mt)
#pragma unroll
            for (int nt = 0; nt < NT; ++nt)
                acc[mt][nt] = __builtin_amdgcn_mfma_f32_16x16x32_bf16(
                    af[mt], bfr[nt], acc[mt][nt], 0, 0, 0);
        __syncthreads();
        p ^= 1;
    }

    float bb[NT];
#pragma unroll
    for (int nt = 0; nt < NT; ++nt) bb[nt] = bias[n0 + wn + nt * 16 + ln];
#pragma unroll
    for (int mt = 0; mt < 4; ++mt)
#pragma unroll
        for (int nt = 0; nt < NT; ++nt) {
            int col = n0 + wn + nt * 16 + ln;
            float sc = (col < nscale) ? smul : 1.f;
#pragma unroll
            for (int rg = 0; rg < 4; ++rg) {
                int row = m0 + wm + mt * 16 + quad * 4 + rg;
                float v = (acc[mt][nt][rg] + bb[nt]) * sc;
                if (OUT_BF16)
                    ((unsigned short*)C)[(size_t)row * N + col] = f2bf(v);
                else
                    ((float*)C)[(size_t)row * N + col] = v;
            }
        }
}

// Differential attention, v6 machinery + VALU trim. Wave owns 16 q-rows;
// block = 64 q-rows; grid (32,32).
__global__ __launch_bounds__(256) void diff_attn_v9(
    const unsigned short* __restrict__ qkv,   // [B*L][3072] bf16 (Q pre-scaled by log2e/32)
    const unsigned short* __restrict__ vdt,   // [B*H][64][2048] bf16
    const float* __restrict__ lam_p,
    unsigned short* __restrict__ o_ws)        // [B*L][1024] bf16
{
    constexpr int L = 2048, TD = 3072;

    __shared__ unsigned short Ks[2][64][64];  // [seq][dh], chunk-swizzled
    __shared__ unsigned short Vs[2][64][64];  // [dh][seq], chunk-swizzled

    const int tid = threadIdx.x;
    const int wave = tid >> 6, lane = tid & 63;
    const int quad = lane >> 4, ln = lane & 15;
    const int bh = blockIdx.y, b = bh >> 4, h = bh & 15;
    const int q0 = blockIdx.x * 64;
    const size_t seqbase = (size_t)b * L;
    const unsigned short* base = qkv + seqbase * TD + h * 64;
    const unsigned short* vbase = vdt + (size_t)bh * 64 * 2048;

    const int lsl = lane >> 3;
    const int cgl = (lane & 7) ^ lsl;

    // Q fragments (B-operand of S^T MFMA: n=ln -> q, k=quad*8+u -> d)
    s16x8 qf0, qf1;
    {
        const unsigned short* qrow = base + (size_t)(q0 + wave * 16 + ln) * TD;
        qf0 = *(const s16x8*)(qrow + quad * 8);
        qf1 = *(const s16x8*)(qrow + 32 + quad * 8);
    }

    // Incrementing staging pointers (advance by constant stride per tile)
    const unsigned short* kp = base + 1024 + (size_t)(wave * 16 + lsl) * TD + cgl * 8;
    const unsigned short* vp = vbase + (size_t)(wave * 16 + lsl) * 2048 + cgl * 8;

    auto stage = [&](int p) {
        gload16(kp,                  &Ks[p][wave * 16][0]);
        gload16(kp + (size_t)8 * TD, &Ks[p][wave * 16 + 8][0]);
        gload16(vp,            &Vs[p][wave * 16][0]);
        gload16(vp + 8 * 2048, &Vs[p][wave * 16 + 8][0]);
    };

    f32x4 Ot[4];     // O^T accumulators: q=ln, d = mt*16 + quad*4 + rg
    f32x4 lacc;      // row-sum accumulator via ones-MFMA (all rg equal)
    lacc = f32x4{0.f, 0.f, 0.f, 0.f};
#pragma unroll
    for (int mt = 0; mt < 4; ++mt) Ot[mt] = f32x4{0.f, 0.f, 0.f, 0.f};

    const s16x8 ones8 = {(short)0x3F80, (short)0x3F80, (short)0x3F80, (short)0x3F80,
                         (short)0x3F80, (short)0x3F80, (short)0x3F80, (short)0x3F80};
    const int kx0 = (quad ^ (ln & 7)) << 3;        // chunk quad
    const int kx1 = ((quad + 4) ^ (ln & 7)) << 3;  // chunk quad+4

    stage(0);
    kp += 64 * TD; vp += 64;
    __syncthreads();
    int p = 0;
    for (int kt = 0; kt < 32; ++kt) {
        if (kt + 1 < 32) { stage(p ^ 1); kp += 64 * TD; vp += 64; }

        // ---- S^T = K Q^T: A = K-frag (m=j), B = qf (n=q).
        //      C-layout: col=ln -> q, row=quad*4+rg -> j = t*16 + quad*4 + rg
        f32x4 ST[4];
#pragma unroll
        for (int t = 0; t < 4; ++t) {
            s16x8 k0 = *(const s16x8*)&Ks[p][t * 16 + ln][kx0];
            s16x8 k1 = *(const s16x8*)&Ks[p][t * 16 + ln][kx1];
            f32x4 z = f32x4{0.f, 0.f, 0.f, 0.f};
            z = __builtin_amdgcn_mfma_f32_16x16x32_bf16(k0, qf0, z, 0, 0, 0);
            z = __builtin_amdgcn_mfma_f32_16x16x32_bf16(k1, qf1, z, 0, 0, 0);
            ST[t] = z;
        }

        // ---- P^T = exp2(S^T); pack hi-16 pairs with v_perm_b32 (1 op/pair) ----
        uint2 pk[4];
#pragma unroll
        for (int t = 0; t < 4; ++t) {
            unsigned int e0 = __builtin_bit_cast(unsigned int, __builtin_amdgcn_exp2f(ST[t][0]));
            unsigned int e1 = __builtin_bit_cast(unsigned int, __builtin_amdgcn_exp2f(ST[t][1]));
            unsigned int e2 = __builtin_bit_cast(unsigned int, __builtin_amdgcn_exp2f(ST[t][2]));
            unsigned int e3 = __builtin_bit_cast(unsigned int, __builtin_amdgcn_exp2f(ST[t][3]));
            // d = { hi16(e_odd), hi16(e_even) }: pool idx 4-7 = first arg bytes
            pk[t].x = __builtin_amdgcn_perm(e1, e0, 0x07060302u);
            pk[t].y = __builtin_amdgcn_perm(e3, e2, 0x07060302u);
        }

        // ---- C-frag -> x32 B-frag relayout via permlane swaps (gfx950 VALU) ----
        s16x8 pfr[2];
#pragma unroll
        for (int bb = 0; bb < 2; ++bb) {
            unsigned int a0 = pk[2 * bb].x, b0 = pk[2 * bb + 1].x;
            unsigned int a1 = pk[2 * bb].y, b1 = pk[2 * bb + 1].y;
            asm volatile("v_permlane32_swap_b32 %0, %1" : "+v"(a0), "+v"(b0));
            asm volatile("v_permlane16_swap_b32 %0, %1" : "+v"(a0), "+v"(b0));
            asm volatile("v_permlane32_swap_b32 %0, %1" : "+v"(a1), "+v"(b1));
            asm volatile("v_permlane16_swap_b32 %0, %1" : "+v"(a1), "+v"(b1));
            uint4 fr = make_uint4(a0, a1, b0, b1);
            pfr[bb] = __builtin_bit_cast(s16x8, fr);
        }

        // ---- row sums l[q] += sum_j P^T[j][q] via ones-MFMA ----
        lacc = __builtin_amdgcn_mfma_f32_16x16x32_bf16(ones8, pfr[0], lacc, 0, 0, 0);
        lacc = __builtin_amdgcn_mfma_f32_16x16x32_bf16(ones8, pfr[1], lacc, 0, 0, 0);

        // ---- O^T += Vd^T P^T (A = Vd^T b128 frag, conflict-free slots) ----
#pragma unroll
        for (int bb = 0; bb < 2; ++bb) {
            const int kx = bb ? kx1 : kx0;   // chunk 4*bb + quad
#pragma unroll
            for (int mt = 0; mt < 4; ++mt) {
                s16x8 vf = *(const s16x8*)&Vs[p][mt * 16 + ln][kx];
                Ot[mt] = __builtin_amdgcn_mfma_f32_16x16x32_bf16(vf, pfr[bb], Ot[mt], 0, 0, 0);
            }
        }
        __syncthreads();
        p ^= 1;
    }

    const float lam = lam_p[0];
    {
        float inv = lam / lacc[0];
        int row = q0 + wave * 16 + ln;
        unsigned short* orow = o_ws + (seqbase + row) * 1024 + h * 64 + quad * 4;
#pragma unroll
        for (int mt = 0; mt < 4; ++mt) {
            ushort4 u;
            u.x = f2bf(Ot[mt][0] * inv);
            u.y = f2bf(Ot[mt][1] * inv);
            u.z = f2bf(Ot[mt][2] * inv);
            u.w = f2bf(Ot[mt][3] * inv);
            *(ushort4*)(orow + mt * 16) = u;
        }
    }
}

extern "C" void kernel_launch(void* const* d_in, const int* in_sizes, int n_in,
                              void* d_out, int out_size, void* d_ws, size_t ws_size,
                              hipStream_t stream) {
    const float* x     = (const float*)d_in[0];
    const float* w_qkv = (const float*)d_in[1];
    const float* b_qkv = (const float*)d_in[2];
    const float* w_out = (const float*)d_in[3];
    const float* b_out = (const float*)d_in[4];
    const float* lam   = (const float*)d_in[5];
    float* out = (float*)d_out;

    unsigned short* xb   = (unsigned short*)d_ws;
    unsigned short* wqb  = xb   + (size_t)4096 * 1024;
    unsigned short* wob  = wqb  + (size_t)3072 * 1024;
    unsigned short* qkvb = wob  + (size_t)1024 * 1024;
    unsigned short* ob   = qkvb + (size_t)4096 * 3072;
    unsigned short* vdt  = ob   + (size_t)4096 * 1024;

    cvt_all<<<8192, 256, 0, stream>>>(x, w_qkv, w_out, xb, wqb, wob);

    // qkv = x @ w_qkv^T + b_qkv; Q cols (n<1024) pre-scaled by log2(e)/32
    // 128x128 tiles (measured best: R6 vs R8 A/B)
    gemm_nt_mfma<1, 128><<<dim3(24, 32), 256, 0, stream>>>(
        xb, wqb, b_qkv, qkvb, 4096, 3072, 1024, 1024, 0.045084222f);

    vd_transpose<<<dim3(32, 32), 256, 0, stream>>>(qkvb, vdt);

    diff_attn_v9<<<dim3(32, 32), 256, 0, stream>>>(qkvb, vdt, lam, ob);

    gemm_nt_mfma<0, 64><<<dim3(16, 32), 256, 0, stream>>>(
        ob, wob, b_out, out, 4096, 1024, 1024, 0, 1.f);
}